// Round 2
// baseline (487.251 us; speedup 1.0000x reference)
//
#include <hip/hip_runtime.h>

// score[i] = dot(x[src[i]], W1) + dot(x[dst[i]], W2) + dot(e[i], W3) + b
// Factored: per-node s[n]=x[n].W1, t[n]=x[n].W2 (x read ONCE), then per-edge
// two scalar gathers + one coalesced e-row dot.
//
// R2 changes vs R1 (R1 was latency-bound at 483 us):
//  - 4 rows per wave-iteration: 8 row-loads in flight before any reduce
//  - split-halves reduction: 7 shuffles per PAIR of sums (was 12)
//  - exact-cover launch: 12500 / 40000 waves (was 4096/8192 looping)

constexpr int D = 512;

__device__ __forceinline__ float dot4(const float4 a, const float4 b) {
    return a.x * b.x + a.y * b.y + a.z * b.z + a.w * b.w;
}

// Reduce TWO per-lane values across the 64-lane wave in 7 shuffles.
// Returns: lanes 0-31 hold sum(u), lanes 32-63 hold sum(v).
__device__ __forceinline__ float reduce_pair(float u, float v, int lane) {
    u += __shfl_xor(u, 32, 64);
    v += __shfl_xor(v, 32, 64);
    float z = (lane < 32) ? u : v;   // offsets <32 stay within each half
#pragma unroll
    for (int off = 16; off > 0; off >>= 1) z += __shfl_xor(z, off, 64);
    return z;
}

// One wave per 4 nodes. Lane l covers float4s {l, 64+l} of each 512-wide row
// -> every load instruction is a fully coalesced contiguous 1 KB wave access.
__global__ __launch_bounds__(256) void node_scores_kernel(
    const float* __restrict__ x, const float* __restrict__ W,
    float* __restrict__ s_out, float* __restrict__ t_out, int n_nodes)
{
    const int lane = threadIdx.x & 63;
    const int wave = (blockIdx.x * blockDim.x + threadIdx.x) >> 6;

    const float4* W4 = (const float4*)W;
    const float4 w1a = W4[lane],       w1b = W4[64 + lane];
    const float4 w2a = W4[128 + lane], w2b = W4[192 + lane];

    const int n0 = wave * 4;
    if (n0 >= n_nodes) return;

    float4 xa[4], xb[4];
#pragma unroll
    for (int r = 0; r < 4; ++r) {
        int n = n0 + r;
        if (n >= n_nodes) n = n_nodes - 1;   // wave-uniform clamp, no divergence
        const float4* xr = (const float4*)(x + (size_t)n * D);
        xa[r] = xr[lane];
        xb[r] = xr[64 + lane];
    }
#pragma unroll
    for (int r = 0; r < 4; ++r) {
        const float s = dot4(xa[r], w1a) + dot4(xb[r], w1b);
        const float t = dot4(xa[r], w2a) + dot4(xb[r], w2b);
        const float z = reduce_pair(s, t, lane);
        const int n = n0 + r;
        if (n < n_nodes) {
            if (lane == 0)  s_out[n] = z;   // lanes 0-31 hold s; lane 0 stores
            if (lane == 32) t_out[n] = z;   // lanes 32-63 hold t; lane 32 stores
        }
    }
}

// One wave per 4 edges. Rows paired through reduce_pair (7 shuffles / 2 edges).
// Index + node-score gathers are wave-uniform broadcasts issued alongside the
// row loads so their latency hides under the 8 KB of row fetch in flight.
__global__ __launch_bounds__(256) void edge_scores_kernel(
    const float* __restrict__ e, const int* __restrict__ src,
    const int* __restrict__ dst, const float* __restrict__ W,
    const float* __restrict__ bp, const float* __restrict__ s_in,
    const float* __restrict__ t_in, float* __restrict__ out, int n_edges)
{
    const int lane = threadIdx.x & 63;
    const int wave = (blockIdx.x * blockDim.x + threadIdx.x) >> 6;

    const float4* W4 = (const float4*)W;
    const float4 w3a = W4[256 + lane], w3b = W4[320 + lane];
    const float bias = bp[0];

    const int i0 = wave * 4;
    if (i0 >= n_edges) return;

    float4 ea[4], eb[4];
    float  sv[4];
#pragma unroll
    for (int r = 0; r < 4; ++r) {
        int i = i0 + r;
        if (i >= n_edges) i = n_edges - 1;   // wave-uniform clamp
        const float4* er = (const float4*)(e + (size_t)i * D);
        ea[r] = er[lane];
        eb[r] = er[64 + lane];
        sv[r] = s_in[src[i]] + t_in[dst[i]] + bias;  // broadcast loads, all lanes
    }
#pragma unroll
    for (int r = 0; r < 4; r += 2) {
        const float p0 = dot4(ea[r],     w3a) + dot4(eb[r],     w3b);
        const float p1 = dot4(ea[r + 1], w3a) + dot4(eb[r + 1], w3b);
        const float z  = reduce_pair(p0, p1, lane);
        const int ia = i0 + r, ib = i0 + r + 1;
        if (lane == 0  && ia < n_edges) out[ia] = z + sv[r];
        if (lane == 32 && ib < n_edges) out[ib] = z + sv[r + 1];
    }
}

extern "C" void kernel_launch(void* const* d_in, const int* in_sizes, int n_in,
                              void* d_out, int out_size, void* d_ws, size_t ws_size,
                              hipStream_t stream) {
    const float* x   = (const float*)d_in[0];
    const float* e   = (const float*)d_in[1];
    const int*   src = (const int*)d_in[2];
    const int*   dst = (const int*)d_in[3];
    const float* W   = (const float*)d_in[4];
    const float* b   = (const float*)d_in[5];

    const int n_nodes = in_sizes[0] / D;   // 50000
    const int n_edges = in_sizes[2];       // 160000

    float* s   = (float*)d_ws;             // [n_nodes]
    float* t   = s + n_nodes;              // [n_nodes]
    float* out = (float*)d_out;            // [n_edges]

    // Exact cover: 4 nodes per wave -> ceil(50000/16) = 3125 blocks of 4 waves.
    const int node_blocks = (n_nodes + 15) / 16;
    node_scores_kernel<<<node_blocks, 256, 0, stream>>>(x, W, s, t, n_nodes);

    // 4 edges per wave -> ceil(160000/16) = 10000 blocks.
    const int edge_blocks = (n_edges + 15) / 16;
    edge_scores_kernel<<<edge_blocks, 256, 0, stream>>>(e, src, dst, W, b, s, t, out, n_edges);
}